// Round 16
// baseline (193.601 us; speedup 1.0000x reference)
//
#include <hip/hip_runtime.h>
#include <hip/hip_bf16.h>
#include <stdint.h>

// Problem constants (match reference)
#define B_SZ 8
#define T_LEN 1024
#define C_DIM 1024
#define M_ROWS (B_SZ * T_LEN)   // 8192
#define NCH 32
#define CHL (T_LEN / NCH)       // 32

typedef unsigned short ushort_t;
typedef __attribute__((ext_vector_type(8))) short short8;
typedef __attribute__((ext_vector_type(4))) float f32x4;
typedef __attribute__((ext_vector_type(4))) unsigned short us4;

static __device__ __forceinline__ float bf2f(ushort_t u) {
  union { unsigned int i; float f; } x; x.i = ((unsigned int)u) << 16; return x.f;
}
static __device__ __forceinline__ ushort_t f2bf(float f) {
  union { float f; unsigned int i; } x; x.f = f;
  unsigned int r = x.i + 0x7fffu + ((x.i >> 16) & 1u);
  return (ushort_t)(r >> 16);
}

static __device__ __forceinline__ void gload_lds16(const void* g, void* l) {
  __builtin_amdgcn_global_load_lds(
      (const __attribute__((address_space(1))) void*)g,
      (__attribute__((address_space(3))) void*)l, 16, 0, 0);
}

// -------- merged prep: weight f32->bf16 (4 mats) + time-shift mix ----------
__global__ void prep_kernel(const float* __restrict__ wk, const float* __restrict__ wv,
                            const float* __restrict__ wr, const float* __restrict__ wo,
                            ushort_t* __restrict__ wout,
                            const float* __restrict__ x, const float* __restrict__ tm,
                            const float* __restrict__ cm, ushort_t* __restrict__ xmb) {
  if (blockIdx.x < 4096) {
    int gid = blockIdx.x * 256 + threadIdx.x;
    int which = gid >> 18;
    int off = (gid << 2) & ((1 << 20) - 1);
    const float* src = which == 0 ? wk : which == 1 ? wv : which == 2 ? wr : wo;
    float4 v = *(const float4*)(src + off);
    us4 o = {f2bf(v.x), f2bf(v.y), f2bf(v.z), f2bf(v.w)};
    *(us4*)(wout + (size_t)gid * 4) = o;
  } else {
    int gid = (blockIdx.x - 4096) * 256 + threadIdx.x;
    int c4 = (gid & (C_DIM / 4 - 1)) * 4;
    int t = (gid >> 8) & (T_LEN - 1);
    const float4 zero = {0.f, 0.f, 0.f, 0.f};
    float4 xv = *(const float4*)(x + (size_t)gid * 4);
    float4 xp = (t > 0) ? *(const float4*)(x + (size_t)gid * 4 - C_DIM) : zero;
    float4 xn = (t < T_LEN - 1) ? *(const float4*)(x + (size_t)gid * 4 + C_DIM) : zero;
    float4 tmv = *(const float4*)(tm + c4);
    float4 cmv = *(const float4*)(cm + c4);
    float4 xc = (c4 < C_DIM / 2) ? xp : xn;
    us4 o;
    o.x = f2bf(xv.x * tmv.x + xp.x * (1.f - tmv.x) + xc.x * cmv.x);
    o.y = f2bf(xv.y * tmv.y + xp.y * (1.f - tmv.y) + xc.y * cmv.y);
    o.z = f2bf(xv.z * tmv.z + xp.z * (1.f - tmv.z) + xc.z * cmv.z);
    o.w = f2bf(xv.w * tmv.w + xp.w * (1.f - tmv.w) + xc.w * cmv.w);
    *(us4*)(xmb + (size_t)gid * 4) = o;
  }
}

// ==== fused k/v/r GEMM: 256x128, BK=32, 8 waves, 3-buf counted vmcnt ========
// Exact R11 structure (measured best: fused ~88us / 586 TF).
__global__ __launch_bounds__(512, 4) void gemm_fused(const ushort_t* __restrict__ A,
                                                     const ushort_t* __restrict__ Bw,
                                                     ushort_t* __restrict__ outK,
                                                     ushort_t* __restrict__ outV,
                                                     ushort_t* __restrict__ outR) {
  constexpr int K = 1024;
  __shared__ ushort_t As[3][256 * 32];   // 48 KB
  __shared__ ushort_t Bs[3][128 * 32];   // 24 KB

  const int tid = threadIdx.x;
  const int lane = tid & 63;
  const int wid = tid >> 6;
  const int wm = wid & 3;
  const int wn = wid >> 2;

  const int bid = blockIdx.x;
  const int xcd = bid & 7;
  const int c = bid >> 3;
  const int bm = (xcd * 4 + (c & 3)) * 256;
  const int jb = c >> 2;
  const int mode = jb >> 3;
  const int bn = (jb & 7) * 128;
  const ushort_t* Bp = Bw + ((size_t)mode << 20);

  const int wr = wm * 64;
  const int wc = wn * 64;

  f32x4 acc[4][4];
#pragma unroll
  for (int m = 0; m < 4; ++m)
#pragma unroll
    for (int n = 0; n < 4; ++n) acc[m][n] = (f32x4){0.f, 0.f, 0.f, 0.f};

  const int a0r = tid >> 2, a0c = (((tid & 3) ^ ((tid >> 3) & 3)) * 8);
  const int c1 = tid + 512;
  const int a1r = c1 >> 2, a1c = (((c1 & 3) ^ ((c1 >> 3) & 3)) * 8);
  const ushort_t* Ag0 = A + (size_t)(bm + a0r) * K + a0c;
  const ushort_t* Ag1 = A + (size_t)(bm + a1r) * K + a1c;
  const ushort_t* Bg = Bp + (size_t)(bn + a0r) * K + a0c;

  const int fr = lane & 15;
  const int kq = lane >> 4;
  const int ps = (kq ^ ((fr >> 1) & 3)) * 8;

  auto stage = [&](int buf, int kt) {
    const int k0 = kt * 32;
    gload_lds16(Ag0 + k0, &As[buf][tid * 8]);
    gload_lds16(Ag1 + k0, &As[buf][(tid + 512) * 8]);
    gload_lds16(Bg + k0, &Bs[buf][tid * 8]);
  };

#define MFMA_STEP(BUF)                                                        \
  {                                                                           \
    short8 af[4], bfr[4];                                                     \
    _Pragma("unroll") for (int m = 0; m < 4; ++m)                             \
        af[m] = *(const short8*)&As[BUF][(wr + m * 16 + fr) * 32 + ps];       \
    _Pragma("unroll") for (int n = 0; n < 4; ++n)                             \
        bfr[n] = *(const short8*)&Bs[BUF][(wc + n * 16 + fr) * 32 + ps];      \
    _Pragma("unroll") for (int m = 0; m < 4; ++m)                             \
        _Pragma("unroll") for (int n = 0; n < 4; ++n)                         \
            acc[m][n] = __builtin_amdgcn_mfma_f32_16x16x32_bf16(              \
                af[m], bfr[n], acc[m][n], 0, 0, 0);                           \
  }

#define ENDSTEP(N)                                                            \
  asm volatile("s_waitcnt vmcnt(" #N ")" ::: "memory");                       \
  __builtin_amdgcn_s_barrier();                                               \
  __builtin_amdgcn_sched_barrier(0);

#define BODY(ACUR, ASTG, T)                                                   \
  stage(ASTG, (T) + 2);                                                       \
  MFMA_STEP(ACUR);                                                            \
  ENDSTEP(3)

  stage(0, 0);
  stage(1, 1);
  ENDSTEP(3)

#pragma unroll 1
  for (int i = 0; i < 10; ++i) {
    const int t0 = 3 * i;
    BODY(0, 2, t0 + 0)
    BODY(1, 0, t0 + 1)
    BODY(2, 1, t0 + 2)
  }
  MFMA_STEP(0);
  ENDSTEP(0)
  MFMA_STEP(1);

#pragma unroll
  for (int m = 0; m < 4; ++m)
#pragma unroll
    for (int n = 0; n < 4; ++n)
#pragma unroll
      for (int j = 0; j < 4; ++j) {
        float v = acc[m][n][j];
        size_t idx = (size_t)(bm + wr + m * 16 + kq * 4 + j) * C_DIM + (bn + wc + n * 16 + fr);
        if (mode == 0) {
          outK[idx] = f2bf(__expf(fminf(v, 60.f)));
        } else if (mode == 1) {
          outV[idx] = f2bf(v);
        } else {
          outR[idx] = f2bf(1.f / (1.f + __expf(-v)));
        }
      }
#undef BODY
#undef ENDSTEP
#undef MFMA_STEP
}

// ==== output GEMM: R6 structure (128x128, BK=32, 3-buf, vmcnt(4)) ==========
__global__ __launch_bounds__(256, 3) void gemm_out(const ushort_t* __restrict__ A,
                                                   const ushort_t* __restrict__ Bw,
                                                   float* __restrict__ outF) {
  constexpr int K = 1024;
  constexpr int NT = K / 32;
  __shared__ ushort_t As[3][128 * 32];
  __shared__ ushort_t Bs[3][128 * 32];

  const int tid = threadIdx.x;
  const int lane = tid & 63;
  const int wave = tid >> 6;

  const int bid = blockIdx.x;
  const int xcd = bid & 7;
  const int r = bid >> 3;
  const int bm = (xcd * 8 + (r & 7)) * 128;
  const int bn = (r >> 3) * 128;

  const int wr = (wave >> 1) * 64;
  const int wc = (wave & 1) * 64;

  f32x4 acc[4][4];
#pragma unroll
  for (int m = 0; m < 4; ++m)
#pragma unroll
    for (int n = 0; n < 4; ++n) acc[m][n] = (f32x4){0.f, 0.f, 0.f, 0.f};

  const int srow = tid >> 2;
  const int scol = (((tid & 3) ^ ((srow >> 1) & 3)) * 8);
  const ushort_t* Ag = A + (size_t)(bm + srow) * K + scol;
  const ushort_t* Bg = Bw + (size_t)(bn + srow) * K + scol;

  const int fr = lane & 15;
  const int kq = lane >> 4;
  const int ps = (kq ^ ((fr >> 1) & 3)) * 8;

  auto stage = [&](int buf, int kt) {
    const int k0 = kt * 32;
    ushort_t* ap = &As[buf][tid * 8];
    ushort_t* bp = &Bs[buf][tid * 8];
    gload_lds16(Ag + k0, ap);
    gload_lds16(Ag + (size_t)64 * K + k0, ap + 64 * 32);
    gload_lds16(Bg + k0, bp);
    gload_lds16(Bg + (size_t)64 * K + k0, bp + 64 * 32);
  };

  stage(0, 0);
  stage(1, 1);
  asm volatile("s_waitcnt vmcnt(4)" ::: "memory");
  __builtin_amdgcn_s_barrier();
  __builtin_amdgcn_sched_barrier(0);

  int cur = 0, nxt2 = 2;
#pragma unroll 1
  for (int t = 0; t < NT; ++t) {
    if (t + 2 < NT) stage(nxt2, t + 2);
    const ushort_t* asb = &As[cur][0];
    const ushort_t* bsb = &Bs[cur][0];
    short8 af[4], bfr[4];
#pragma unroll
    for (int m = 0; m < 4; ++m)
      af[m] = *(const short8*)&asb[(wr + m * 16 + fr) * 32 + ps];
#pragma unroll
    for (int n = 0; n < 4; ++n)
      bfr[n] = *(const short8*)&bsb[(wc + n * 16 + fr) * 32 + ps];
#pragma unroll
    for (int m = 0; m < 4; ++m)
#pragma unroll
      for (int n = 0; n < 4; ++n)
        acc[m][n] = __builtin_amdgcn_mfma_f32_16x16x32_bf16(af[m], bfr[n], acc[m][n], 0, 0, 0);
    if (t + 2 < NT) {
      asm volatile("s_waitcnt vmcnt(4)" ::: "memory");
    } else {
      asm volatile("s_waitcnt vmcnt(0)" ::: "memory");
    }
    __builtin_amdgcn_s_barrier();
    __builtin_amdgcn_sched_barrier(0);
    cur = (cur == 2) ? 0 : cur + 1;
    nxt2 = (nxt2 == 2) ? 0 : nxt2 + 1;
  }

#pragma unroll
  for (int m = 0; m < 4; ++m)
#pragma unroll
    for (int n = 0; n < 4; ++n)
#pragma unroll
      for (int j = 0; j < 4; ++j)
        outF[(size_t)(bm + wr + m * 16 + kq * 4 + j) * C_DIM + (bn + wc + n * 16 + fr)] =
            acc[m][n][j];
}

// ---------------- wkv: single-kernel block-local scan -----------------------
// Block = (b, 32-channel group), 1024 threads = 32 chunks x 32 channels.
// All 32 chunks of a (b,c) live in ONE block -> __syncthreads replaces the
// R15 grid.sync (which hung graph capture). Thread scans its chunk with
// kk/vv held in 64 statically-indexed registers, publishes (a,b,p) to LDS,
// syncs, prefix-combines chunks < ch from LDS, then emits sigmoid(r)*y
// from the registered chunk. kk/vv read ONCE; states never touch HBM.
__global__ __launch_bounds__(1024) void wkv_fused(const ushort_t* __restrict__ kk,
                                                  const ushort_t* __restrict__ vv,
                                                  const ushort_t* __restrict__ sr,
                                                  const float* __restrict__ td,
                                                  const float* __restrict__ tf,
                                                  ushort_t* __restrict__ sy) {
  __shared__ float lsa[NCH][32];
  __shared__ float lsb[NCH][32];
  __shared__ float lsp[NCH][32];

  const int tid = threadIdx.x;
  const int cl = tid & 31;         // channel within group
  const int ch = tid >> 5;         // chunk 0..31
  const int bid = blockIdx.x;
  const int b = bid >> 5;
  const int cg = bid & 31;
  const int c = cg * 32 + cl;

  const float w = td[c] * (1.f / T_LEN);
  const float u = tf[c] * (1.f / T_LEN);
  const float wL = w * (float)CHL;
  const size_t base = ((size_t)b * T_LEN + ch * CHL) * C_DIM + c;

  // load chunk into registers (statically indexed -> VGPRs)
  float kr[CHL], vr[CHL];
#pragma unroll
  for (int t = 0; t < CHL; ++t) {
    kr[t] = bf2f(kk[base + (size_t)t * C_DIM]);
    vr[t] = bf2f(vv[base + (size_t)t * C_DIM]);
  }

  // chunk-local scan from zero init -> LDS state
  {
    float a = 0.f, bb = 0.f, p = -1e38f;
#pragma unroll
    for (int t = 0; t < CHL; ++t) {
      float no2 = fmaxf(w + p, kr[t]);
      float e1 = __expf(w + p - no2);
      float e2 = __expf(kr[t] - no2);
      a = e1 * a + e2 * vr[t];
      bb = e1 * bb + e2;
      p = no2;
    }
    lsa[ch][cl] = a; lsb[ch][cl] = bb; lsp[ch][cl] = p;
  }

  __syncthreads();

  // prefix-combine chunks < ch (LDS, conflict-free: cl consecutive)
  float a = 0.f, bb = 0.f, p = -1e38f;
  for (int j = 0; j < ch; ++j) {
    float ac = lsa[j][cl], bc = lsb[j][cl], pc = lsp[j][cl];
    float pn = fmaxf(p + wL, pc);
    float e1 = __expf(p + wL - pn);
    float e2 = __expf(pc - pn);
    a = e1 * a + e2 * ac;
    bb = e1 * bb + e2 * bc;
    p = pn;
  }

  // emit pass, reusing registered kk/vv
#pragma unroll
  for (int t = 0; t < CHL; ++t) {
    float no = fmaxf(p, u + kr[t]);
    float e1 = __expf(p - no);
    float e2 = __expf(u + kr[t] - no);
    float y = (e1 * a + e2 * vr[t]) / (e1 * bb + e2);
    float srv = bf2f(sr[base + (size_t)t * C_DIM]);
    sy[base + (size_t)t * C_DIM] = f2bf(srv * y);
    float no2 = fmaxf(w + p, kr[t]);
    e1 = __expf(w + p - no2);
    e2 = __expf(kr[t] - no2);
    a = e1 * a + e2 * vr[t];
    bb = e1 * bb + e2;
    p = no2;
  }
}

// ---------------------------------------------------------------------------
extern "C" void kernel_launch(void* const* d_in, const int* in_sizes, int n_in,
                              void* d_out, int out_size, void* d_ws, size_t ws_size,
                              hipStream_t stream) {
  const float* x  = (const float*)d_in[0];
  const float* td = (const float*)d_in[1];
  const float* tf = (const float*)d_in[2];
  const float* tm = (const float*)d_in[3];
  const float* cm = (const float*)d_in[4];
  const float* Wk = (const float*)d_in[5];
  const float* Wv = (const float*)d_in[6];
  const float* Wr = (const float*)d_in[7];
  const float* Wo = (const float*)d_in[8];

  const size_t MC = (size_t)M_ROWS * C_DIM;
  const size_t CC = (size_t)C_DIM * C_DIM;

  char* ws = (char*)d_ws;
  ushort_t* xmb = (ushort_t*)ws; ws += MC * 2;
  ushort_t* Wb  = (ushort_t*)ws; ws += 4 * CC * 2;
  ushort_t* kk  = (ushort_t*)ws; ws += MC * 2;
  ushort_t* vv  = (ushort_t*)ws; ws += MC * 2;
  ushort_t* sr  = (ushort_t*)ws; ws += MC * 2;
  ushort_t* sy  = (ushort_t*)ws; ws += MC * 2;

  prep_kernel<<<dim3(12288), 256, 0, stream>>>(Wk, Wv, Wr, Wo, Wb, x, tm, cm, xmb);

  // fused k/v/r projections: 256x128 tiles, 768 blocks, 3-buf counted vmcnt
  gemm_fused<<<dim3(768), 512, 0, stream>>>(xmb, Wb, kk, vv, sr);

  // wkv scan: single kernel, block-local chunks, kk/vv read once
  wkv_fused<<<dim3(256), 1024, 0, stream>>>(kk, vv, sr, td, tf, sy);

  // output projection: R6 pipeline, 512 blocks fully resident @ 3/CU
  gemm_out<<<dim3(512), 256, 0, stream>>>(sy, Wb + 3 * CC, (float*)d_out);
}